// Round 3
// baseline (498.603 us; speedup 1.0000x reference)
//
#include <hip/hip_runtime.h>

// DynamicUpsamplingFilter, float32.
//   out[n][c*16+u][h][w] = sum_{i,j} xpad[n][c][h+i][w+j] * filters[n][i*5+j][u][h][w]
// x (4,3,180,320), filters (4,25,16,180,320)=368.6MB read-once, out (4,48,180,320)=44.2MB.
//
// R3 structure: block = (n, u, 4-row h-band), 320 threads (5 waves).
//  Phase A: stage x slab (3c x 8 rows x 328 cols) into LDS (31.5 KB) with float4.
//  Phase B: p-loop over 25 taps; each tap's filter read is a 5 KB contiguous run
//           per block (1 KB per wave instr, runs merge across waves/rows since
//           [h][w] is flat). x windows come from LDS (ds_read_b128, 2-way = free).
//  3 coalesced float4 stores per thread. No global x reads in the hot loop.

#define HH 180
#define WW 320
#define CC 3
#define UU 16
#define NN 4
#define HP (HH + 4)          // 184
#define WP 328               // padded row: 320 + 4 halo + 4 align slack (82*16B)
#define HW (HH * WW)         // 57600
#define RB 4                 // rows per band
#define NBANDS (HH / RB)     // 45
#define BT 320               // threads per block (5 waves)
#define SLAB_ROWS (RB + 4)   // 8 rows of xpad per band

__global__ __launch_bounds__(256) void pad_x_kernel(
    const float* __restrict__ x, float* __restrict__ xpad)
{
    int idx = blockIdx.x * 256 + threadIdx.x;   // grid sized exactly: 4*3*184*328
    int wp = idx % WP;
    int t  = idx / WP;
    int hp = t % HP;
    int nc = t / HP;
    int h = hp - 2, w = wp - 2;
    float v = 0.f;
    if (h >= 0 && h < HH && w >= 0 && w < WW)
        v = x[(size_t)nc * HW + h * WW + w];
    xpad[idx] = v;
}

__global__ __launch_bounds__(BT) void duf_kernel(
    const float* __restrict__ xpad,
    const float* __restrict__ filters,
    float* __restrict__ out)
{
    __shared__ float xl[CC * SLAB_ROWS * WP];   // 3*8*328 = 7872 floats = 31488 B

    const int tid = threadIdx.x;
    int b = blockIdx.x;                  // b = ((n*UU + u)*NBANDS + band)
    const int band = b % NBANDS;
    int t = b / NBANDS;
    const int u = t % UU;
    const int n = t / UU;
    const int h0 = band * RB;

    // ---- Phase A: stage x slab into LDS (float4 everywhere, all aligned) ----
    {
        const float* xsrc = xpad + ((size_t)n * CC * HP + h0) * WP;
        const int groups = CC * SLAB_ROWS * (WP / 4);   // 1968
        for (int g = tid; g < groups; g += BT) {
            int colg = g % (WP / 4);
            int rr   = (g / (WP / 4)) % SLAB_ROWS;
            int c    = g / (WP / 4) / SLAB_ROWS;
            float4 v = *(const float4*)(xsrc + ((size_t)c * HP + rr) * WP + colg * 4);
            *(float4*)(&xl[(c * SLAB_ROWS + rr) * WP + colg * 4]) = v;
        }
    }
    __syncthreads();

    // ---- Phase B ----
    const int w4 = tid % (WW / 4);       // 0..79
    const int r  = tid / (WW / 4);       // 0..3
    const int wbase = w4 * 4;
    const int flat = (h0 + r) * WW + wbase;

    // filters[n][p][u][h][w] = base + p*(UU*HW); wave-contiguous in flat
    const float* fbase = filters + ((size_t)n * 25 * UU + u) * HW + flat;

    float acc[CC][4];
    #pragma unroll
    for (int c = 0; c < CC; ++c)
        #pragma unroll
        for (int q = 0; q < 4; ++q) acc[c][q] = 0.f;

    #pragma unroll
    for (int i = 0; i < 5; ++i) {
        float xv[CC][8];
        #pragma unroll
        for (int c = 0; c < CC; ++c) {
            const float* ls = &xl[(c * SLAB_ROWS + r + i) * WP + wbase];
            float4 a = *(const float4*)ls;
            float4 bq = *(const float4*)(ls + 4);
            xv[c][0] = a.x;  xv[c][1] = a.y;  xv[c][2] = a.z;  xv[c][3] = a.w;
            xv[c][4] = bq.x; xv[c][5] = bq.y; xv[c][6] = bq.z; xv[c][7] = bq.w;
        }
        #pragma unroll
        for (int j = 0; j < 5; ++j) {
            float4 f = *(const float4*)(fbase + (size_t)(i * 5 + j) * UU * HW);
            #pragma unroll
            for (int c = 0; c < CC; ++c) {
                acc[c][0] += xv[c][j + 0] * f.x;
                acc[c][1] += xv[c][j + 1] * f.y;
                acc[c][2] += xv[c][j + 2] * f.z;
                acc[c][3] += xv[c][j + 3] * f.w;
            }
        }
    }

    // out[n][c*16+u][h][w]
    float* ob = out + ((size_t)n * CC * UU + u) * HW + flat;
    #pragma unroll
    for (int c = 0; c < CC; ++c)
        *(float4*)(ob + (size_t)c * UU * HW) =
            make_float4(acc[c][0], acc[c][1], acc[c][2], acc[c][3]);
}

extern "C" void kernel_launch(void* const* d_in, const int* in_sizes, int n_in,
                              void* d_out, int out_size, void* d_ws, size_t ws_size,
                              hipStream_t stream) {
    const float* x       = (const float*)d_in[0];
    const float* filters = (const float*)d_in[1];
    float* out           = (float*)d_out;
    float* xpad          = (float*)d_ws;            // 4*3*184*328*4 = 2.9 MB

    const int pad_total = NN * CC * HP * WP;        // 724224 = 2829*256
    pad_x_kernel<<<pad_total / 256, 256, 0, stream>>>(x, xpad);

    const int grid = NN * UU * NBANDS;              // 2880 blocks x 320 threads
    duf_kernel<<<grid, BT, 0, stream>>>(xpad, filters, out);
}